// Round 16
// baseline (2414.332 us; speedup 1.0000x reference)
//
#include <hip/hip_runtime.h>
#include <math.h>
#include <stdint.h>

#define BATCH 4096
#define MCAND 50
#define NTOP 32
#define HID 100

typedef __attribute__((ext_vector_type(8))) short bf16x8;
typedef __attribute__((ext_vector_type(16))) float f32x16;
typedef __attribute__((ext_vector_type(2))) float f32x2;
typedef __attribute__((ext_vector_type(2))) unsigned int u32x2;

union FragU { bf16x8 v; unsigned short s[8]; };

__device__ __forceinline__ uint32_t rotl32(uint32_t v, int d){ return (v<<d)|(v>>(32-d)); }

// JAX threefry2x32 core (20 rounds, 5 key injections)
__device__ __forceinline__ void tf2x32(uint32_t k0, uint32_t k1, uint32_t x0, uint32_t x1,
                                       uint32_t &o0, uint32_t &o1){
  uint32_t k2 = k0 ^ k1 ^ 0x1BD11BDAu;
  x0 += k0; x1 += k1;
#define RND(r) { x0 += x1; x1 = rotl32(x1,(r)); x1 ^= x0; }
  RND(13) RND(15) RND(26) RND(6)
  x0 += k1; x1 += k2 + 1u;
  RND(17) RND(29) RND(16) RND(24)
  x0 += k2; x1 += k0 + 2u;
  RND(13) RND(15) RND(26) RND(6)
  x0 += k0; x1 += k1 + 3u;
  RND(17) RND(29) RND(16) RND(24)
  x0 += k1; x1 += k2 + 4u;
  RND(13) RND(15) RND(26) RND(6)
  x0 += k2; x1 += k0 + 5u;
#undef RND
  o0 = x0; o1 = x1;
}

// XLA ErfInv32 (Giles). w = -log1p(-x*x)
__device__ __forceinline__ float erfinv32(float x){
  float w = -log1pf(-x*x);
  float p;
  if (w < 5.0f){
    w = w - 2.5f;
    p = 2.81022636e-08f;
    p = fmaf(p, w, 3.43273939e-07f);
    p = fmaf(p, w, -3.5233877e-06f);
    p = fmaf(p, w, -4.39150654e-06f);
    p = fmaf(p, w, 0.00021858087f);
    p = fmaf(p, w, -0.00125372503f);
    p = fmaf(p, w, -0.00417768164f);
    p = fmaf(p, w, 0.246640727f);
    p = fmaf(p, w, 1.50140941f);
  } else {
    w = sqrtf(w) - 3.0f;
    p = -0.000200214257f;
    p = fmaf(p, w, 0.000100950558f);
    p = fmaf(p, w, 0.00134934322f);
    p = fmaf(p, w, -0.00367342844f);
    p = fmaf(p, w, 0.00573950773f);
    p = fmaf(p, w, -0.0076224613f);
    p = fmaf(p, w, 0.00943887047f);
    p = fmaf(p, w, 1.00167406f);
    p = fmaf(p, w, 2.83297682f);
  }
  return p*x;
}

// 2-plane bf16 split (truncation): x ~= h+m with rel error <= 2^-16
__device__ __forceinline__ void split2(float x, unsigned short &h, unsigned short &m){
  uint32_t xb = __float_as_uint(x);
  h = (unsigned short)(xb >> 16);
  float r = x - __uint_as_float(xb & 0xFFFF0000u);
  m = (unsigned short)(__float_as_uint(r) >> 16);
}

#define MFMA(a,b,c) __builtin_amdgcn_mfma_f32_32x32x16_bf16((a),(b),(c),0,0,0)
// pack high-16s of two fp32: (x0>>16)|(x1&0xFFFF0000) in ONE v_perm_b32
#define PACKHI(x1,x0) __builtin_amdgcn_perm((x1),(x0),0x07060302u)

// DPP lane swaps (quad_perm): xor1 = 0xB1, xor2 = 0x4E. VALU-only (no DS pipe).
#define DPPPERM(v, CTRL) __int_as_float(__builtin_amdgcn_update_dpp( \
    0, __float_as_int(v), (CTRL), 0xF, 0xF, true))
#define DPPADD(v, CTRL) ((v) + DPPPERM((v), (CTRL)))

// packed-fp32 helpers (lower to v_pk_fma_f32 / v_pk_max_f32)
#define PKFMA(a,b,c) __builtin_elementwise_fma((a),(b),(c))
#define PKMAX0(a)    __builtin_elementwise_max((a), (f32x2)(0.0f))

// LDS A-planes: 2 planes x 64 rows x 104 bf16 (208B rows). GEMM reads at the
// wave64 b128 minimum; strip-ownership writes keep sSW/sW13 reads broadcast
// (r14 proved coalesced writes destroy read broadcast at a net loss).
#define AROW 104
#define APLANE (64*AROW)

__global__ __launch_bounds__(256, 3) void cem_kernel(
    const float* __restrict__ states, const float* __restrict__ W1,
    const float* __restrict__ b1,     const float* __restrict__ W2,
    const float* __restrict__ b2,     const float* __restrict__ W3,
    const float* __restrict__ b3,     float* __restrict__ out)
{
  __shared__ __align__(16) unsigned short sApl[2*APLANE]; // 26624 B
  __shared__ float qbuf[2][64];
  __shared__ __align__(16) float sSW[HID];
  __shared__ __align__(16) float sW13[HID];
  __shared__ float sEps[64];
  __shared__ uint32_t sKeys[198];
  __shared__ float sB3;

  const int tid  = threadIdx.x;
  const int b    = blockIdx.x;
  const int wv   = tid >> 6;
  const int lane = tid & 63;
  const int half = lane >> 5;
  const int col  = lane & 31;
  // wave role: one M-tile (32 candidate rows), one N-pair (2 x 32 output cols)
  const int mt   = wv >> 1;            // 0,0,1,1
  const int np   = wv & 1;             // 0,1,0,1
  const int n0   = (2*np)*32 + col;
  const int n1   = (2*np+1)*32 + col;
  const int ewv  = (b + 1) & 3;        // eps wave (block-parity, overlapped)

  const float s0 = states[2*b], s1 = states[2*b+1];

  // zero-init A planes (pads must stay zero)
  for (int f = tid; f < APLANE; f += 256) ((unsigned int*)sApl)[f] = 0u;

  if (tid < HID){
    float w0 = W1[tid], w1 = W1[HID+tid];
    sSW[tid]  = fmaf(s0, w0, fmaf(s1, w1, b1[tid]));
    sW13[tid] = W1[2*HID+tid];
  }
  if (tid == 0) sB3 = b3[0];

  // per-lane epilogue constants (two N-tiles per wave)
  const float bn2_0 = (n0 < HID) ? b2[n0] : 0.0f;
  const float wn3_0 = (n0 < HID) ? W3[n0] : 0.0f;
  const float bn2_1 = (n1 < HID) ? b2[n1] : 0.0f;
  const float wn3_1 = (n1 < HID) ? W3[n1] : 0.0f;

  // one-time: static W2 B-fragments in registers (2-plane bf16 split), 2 N-tiles
  bf16x8 Bfh[2][7], Bfm[2][7];
#pragma unroll
  for (int j = 0; j < 2; ++j){
    const int n = j ? n1 : n0;
#pragma unroll
    for (int ks = 0; ks < 7; ++ks){
      FragU fh, fm;
#pragma unroll
      for (int i = 0; i < 8; ++i){
        int k = ks*16 + half*8 + i;
        float w = (k < HID && n < HID) ? W2[k*HID + n] : 0.0f;
        split2(w, fh.s[i], fm.s[i]);
      }
      Bfh[j][ks] = fh.v; Bfm[j][ks] = fm.v;
    }
  }

  // phase-1 fixed ownership: thread -> (candidate c_own, 20-wide k strip)
  const bool p1act = (tid < 250);
  const int  c_own = tid / 5;            // hoisted division (once)
  const int  k0own = (tid - c_own*5) * 20;
  const int  baseown = c_own*AROW + k0own;
  const int  rbase = (mt*32 + col)*AROW;

  // key schedule: key(42) = (0,42); split -> k0=(A0,B0), kloop=(A1,B1)
  if (tid < 99){
    uint32_t A0,A1,B0,B1;
    tf2x32(0u,42u,0u,2u,A0,A1);
    tf2x32(0u,42u,1u,3u,B0,B1);
    uint32_t o0,o1;
    tf2x32(A1,B1,(uint32_t)tid,(uint32_t)(99+tid),o0,o1);
    sKeys[tid]    = o0;
    sKeys[99+tid] = o1;
    if (tid < MCAND){
      // iteration-0 "eps" = uniform angles (mu=0, std=1 makes a_c = eps_c)
      uint32_t gidx = (uint32_t)b*MCAND + (uint32_t)tid;
      uint32_t r0,r1,bits;
      if (gidx < 102400u){ tf2x32(A0,B0,gidx,gidx+102400u,r0,r1); bits = r0; }
      else               { tf2x32(A0,B0,gidx-102400u,gidx,r0,r1); bits = r1; }
      sEps[tid] = __uint_as_float((bits>>9) | 0x3f800000u) - 1.0f;
    }
  }
  __syncthreads();

  const float MINV = -0x1.fffffep-1f;   // nextafter(-1,0)
  const float SQRT2 = 0x1.6a09e6p+0f;   // fp32 sqrt(2)

  float mu = 0.0f, stdv = 1.0f;         // per-wave redundant CEM state

#pragma unroll 1
  for (int t = 0; t < 99; ++t){
    // ---- phase 1 (packed fp32): h1 = relu(sSW + a*sW13); split2 to LDS ----
    if (p1act){
      const float a = fmaf(stdv, sEps[c_own], mu);
      const f32x2 a2 = {a, a};
#pragma unroll
      for (int i = 0; i < 5; ++i){
        const int k = k0own + 4*i;
        float4 sw  = *(const float4*)&sSW[k];
        float4 w13 = *(const float4*)&sW13[k];
        f32x2 s01 = {sw.x, sw.y},  s23 = {sw.z, sw.w};
        f32x2 w01 = {w13.x, w13.y}, w23 = {w13.z, w13.w};
        f32x2 v01 = PKMAX0(PKFMA(a2, w01, s01));   // v_pk_fma + v_pk_max
        f32x2 v23 = PKMAX0(PKFMA(a2, w23, s23));
        u32x2 x01 = __builtin_bit_cast(u32x2, v01);
        u32x2 x23 = __builtin_bit_cast(u32x2, v23);
        uint2 hq, mq;
        hq.x = PACKHI(x01.y, x01.x);
        hq.y = PACKHI(x23.y, x23.x);
        f32x2 h01 = __builtin_bit_cast(f32x2, x01 & 0xFFFF0000u);
        f32x2 h23 = __builtin_bit_cast(f32x2, x23 & 0xFFFF0000u);
        u32x2 r01 = __builtin_bit_cast(u32x2, v01 - h01);   // v_pk_add (neg)
        u32x2 r23 = __builtin_bit_cast(u32x2, v23 - h23);
        mq.x = PACKHI(r01.y, r01.x);
        mq.y = PACKHI(r23.y, r23.x);
        *(uint2*)&sApl[baseown + 4*i]          = hq;
        *(uint2*)&sApl[APLANE + baseown + 4*i] = mq;
      }
    }
    __syncthreads();   // B1

    // ---- phase 2: next-iter eps (block-parity wave, overlapped) + MFMA GEMM ----
    if (wv == ewv && t < 98 && lane < MCAND){
      uint32_t kk0 = sKeys[2*t], kk1 = sKeys[2*t+1];
      uint32_t gidx = (uint32_t)b*MCAND + (uint32_t)lane;
      uint32_t r0,r1,bits;
      if (gidx < 102400u){ tf2x32(kk0,kk1,gidx,gidx+102400u,r0,r1); bits = r0; }
      else               { tf2x32(kk0,kk1,gidx-102400u,gidx,r0,r1); bits = r1; }
      float fl = __uint_as_float((bits>>9) | 0x3f800000u) - 1.0f;
      float u  = fmaxf(MINV, fl*2.0f + MINV);
      sEps[lane] = SQRT2 * erfinv32(u);
    }

    {
      f32x16 acc0, acc1;   // two N-tiles, same M-tile
#pragma unroll
      for (int r = 0; r < 16; ++r){ acc0[r] = 0.0f; acc1[r] = 0.0f; }

#pragma unroll
      for (int ks = 0; ks < 7; ++ks){
        const int ra = rbase + ks*16 + half*8;
        bf16x8 ah = *(const bf16x8*)&sApl[ra];
        bf16x8 am = *(const bf16x8*)&sApl[APLANE + ra];
        // hh + hm + mh per N-tile (mm dropped: below 2-plane truncation noise)
        acc0 = MFMA(ah, Bfh[0][ks], acc0);
        acc1 = MFMA(ah, Bfh[1][ks], acc1);
        acc0 = MFMA(ah, Bfm[0][ks], acc0);
        acc1 = MFMA(ah, Bfm[1][ks], acc1);
        acc0 = MFMA(am, Bfh[0][ks], acc0);
        acc1 = MFMA(am, Bfh[1][ks], acc1);
      }

      // epilogue (packed fp32): per-N-tile relu+W3 scale, sum the two N-tiles
      float v[16];
      {
        const f32x2 b0p = {bn2_0, bn2_0}, w0p = {wn3_0, wn3_0};
        const f32x2 b1p = {bn2_1, bn2_1}, w1p = {wn3_1, wn3_1};
#pragma unroll
        for (int i = 0; i < 8; ++i){
          f32x2 p0 = {acc0[2*i], acc0[2*i+1]};
          f32x2 p1 = {acc1[2*i], acc1[2*i+1]};
          f32x2 t0 = PKMAX0(p0 + b0p);
          f32x2 t1 = PKMAX0(p1 + b1p);
          f32x2 r  = t0 * w0p + t1 * w1p;   // same expression shape as r15
          v[2*i] = r.x; v[2*i+1] = r.y;
        }
      }
      // concentrated reduction: steps 0,1 on DPP (VALU), steps 2,3 on DS shuffle
      {
        const bool hi0 = (col & 1) != 0;
#pragma unroll
        for (int i = 0; i < 8; ++i){
          float a0 = DPPADD(v[2*i],   0xB1);
          float b0 = DPPADD(v[2*i+1], 0xB1);
          v[i] = hi0 ? b0 : a0;
        }
        const bool hi1 = (col & 2) != 0;
#pragma unroll
        for (int i = 0; i < 4; ++i){
          float a0 = DPPADD(v[2*i],   0x4E);
          float b0 = DPPADD(v[2*i+1], 0x4E);
          v[i] = hi1 ? b0 : a0;
        }
#pragma unroll
        for (int step = 2; step < 4; ++step){
          const int off = 1 << step;
          const bool hi = (col & off) != 0;
          const int nn = 16 >> step;
#pragma unroll
          for (int i = 0; i < nn/2; ++i){
            float a0 = v[2*i]   + __shfl_xor(v[2*i],   off, 64);
            float b0 = v[2*i+1] + __shfl_xor(v[2*i+1], off, 64);
            v[i] = hi ? b0 : a0;
          }
        }
      }
      float red = v[0] + __shfl_xor(v[0], 16, 64);
      const int c15 = col & 15;
      const int row = (c15 & 3) + 8*(c15 >> 2) + 4*half;
      if (col < 16) qbuf[np][mt*32 + row] = red;
    }
    __syncthreads();   // B2

    // ---- phase 3 (redundant on ALL 4 waves, DPP-cheap): top-32 stats in regs ----
    {
      float q = -INFINITY;
      if (lane < MCAND)
        q = qbuf[0][lane] + qbuf[1][lane] + sB3;
      // sort 32-halves in opposite directions, j=32 max-merge -> top-32 multiset
      float v = q;
#define BST(KK, JJ, PV) { float pv = (PV); bool lower = (lane & (JJ)) == 0; \
        bool asc = (lane & (KK)) != 0; float mn = fminf(v, pv), mx = fmaxf(v, pv); \
        v = (lower == asc) ? mn : mx; }
      BST(2, 1,  DPPPERM(v, 0xB1))
      BST(4, 2,  DPPPERM(v, 0x4E))
      BST(4, 1,  DPPPERM(v, 0xB1))
      BST(8, 4,  __shfl_xor(v, 4, 64))
      BST(8, 2,  DPPPERM(v, 0x4E))
      BST(8, 1,  DPPPERM(v, 0xB1))
      BST(16, 8, __shfl_xor(v, 8, 64))
      BST(16, 4, __shfl_xor(v, 4, 64))
      BST(16, 2, DPPPERM(v, 0x4E))
      BST(16, 1, DPPPERM(v, 0xB1))
      BST(32, 16, __shfl_xor(v, 16, 64))
      BST(32, 8,  __shfl_xor(v, 8, 64))
      BST(32, 4,  __shfl_xor(v, 4, 64))
      BST(32, 2,  DPPPERM(v, 0x4E))
      BST(32, 1,  DPPPERM(v, 0xB1))
#undef BST
      {
        float pv = __shfl_xor(v, 32, 64);
        v = ((lane & 32) == 0) ? fmaxf(v, pv) : fminf(v, pv);
      }
      // sum / sum-of-squares over lanes 0..31 (same add order as r13)
      float sv = (lane < NTOP) ? v : 0.0f;
      sv += __shfl_xor(sv, 32, 64);
      sv += __shfl_xor(sv, 16, 64);
      sv += __shfl_xor(sv,  8, 64);
      sv += __shfl_xor(sv,  4, 64);
      sv = DPPADD(sv, 0x4E);
      sv = DPPADD(sv, 0xB1);
      float mun = sv / 32.0f;
      float dv = (lane < NTOP) ? (v - mun) : 0.0f;
      float s2 = dv*dv;
      s2 += __shfl_xor(s2, 32, 64);
      s2 += __shfl_xor(s2, 16, 64);
      s2 += __shfl_xor(s2,  8, 64);
      s2 += __shfl_xor(s2,  4, 64);
      s2 = DPPADD(s2, 0x4E);
      s2 = DPPADD(s2, 0xB1);
      stdv = sqrtf(s2 / 31.0f);
      mu = mun;
      if (t == 98 && tid == 0) out[b] = mu * 6.2831854820251465f;  // fp32(2*pi)
    }
    // no B3: phase1(t+1) sApl writes race only vs phase2(t) reads (behind B2);
    // sEps(t+1) written before B2(t), read after B2(t); qbuf(t+1) written in
    // phase2(t+1) behind B1(t+1), after all phase3(t) reads. (r7-proven.)
  }
}

extern "C" void kernel_launch(void* const* d_in, const int* in_sizes, int n_in,
                              void* d_out, int out_size, void* d_ws, size_t ws_size,
                              hipStream_t stream) {
  const float* states = (const float*)d_in[0];
  const float* W1     = (const float*)d_in[1];
  const float* b1     = (const float*)d_in[2];
  const float* W2     = (const float*)d_in[3];
  const float* b2     = (const float*)d_in[4];
  const float* W3     = (const float*)d_in[5];
  const float* b3     = (const float*)d_in[6];
  float* out = (float*)d_out;
  hipLaunchKernelGGL(cem_kernel, dim3(BATCH), dim3(256), 0, stream,
                     states, W1, b1, W2, b2, W3, b3, out);
}

// Round 17
// 2168.102 us; speedup vs baseline: 1.1136x; 1.1136x over previous
//
#include <hip/hip_runtime.h>
#include <math.h>
#include <stdint.h>

#define BATCH 4096
#define MCAND 50
#define NTOP 32
#define HID 100

typedef __attribute__((ext_vector_type(8))) short bf16x8;
typedef __attribute__((ext_vector_type(16))) float f32x16;

union FragU { bf16x8 v; unsigned short s[8]; };

__device__ __forceinline__ uint32_t rotl32(uint32_t v, int d){ return (v<<d)|(v>>(32-d)); }

// JAX threefry2x32 core (20 rounds, 5 key injections)
__device__ __forceinline__ void tf2x32(uint32_t k0, uint32_t k1, uint32_t x0, uint32_t x1,
                                       uint32_t &o0, uint32_t &o1){
  uint32_t k2 = k0 ^ k1 ^ 0x1BD11BDAu;
  x0 += k0; x1 += k1;
#define RND(r) { x0 += x1; x1 = rotl32(x1,(r)); x1 ^= x0; }
  RND(13) RND(15) RND(26) RND(6)
  x0 += k1; x1 += k2 + 1u;
  RND(17) RND(29) RND(16) RND(24)
  x0 += k2; x1 += k0 + 2u;
  RND(13) RND(15) RND(26) RND(6)
  x0 += k0; x1 += k1 + 3u;
  RND(17) RND(29) RND(16) RND(24)
  x0 += k1; x1 += k2 + 4u;
  RND(13) RND(15) RND(26) RND(6)
  x0 += k2; x1 += k0 + 5u;
#undef RND
  o0 = x0; o1 = x1;
}

// XLA ErfInv32 (Giles). w = -log1p(-x*x)
__device__ __forceinline__ float erfinv32(float x){
  float w = -log1pf(-x*x);
  float p;
  if (w < 5.0f){
    w = w - 2.5f;
    p = 2.81022636e-08f;
    p = fmaf(p, w, 3.43273939e-07f);
    p = fmaf(p, w, -3.5233877e-06f);
    p = fmaf(p, w, -4.39150654e-06f);
    p = fmaf(p, w, 0.00021858087f);
    p = fmaf(p, w, -0.00125372503f);
    p = fmaf(p, w, -0.00417768164f);
    p = fmaf(p, w, 0.246640727f);
    p = fmaf(p, w, 1.50140941f);
  } else {
    w = sqrtf(w) - 3.0f;
    p = -0.000200214257f;
    p = fmaf(p, w, 0.000100950558f);
    p = fmaf(p, w, 0.00134934322f);
    p = fmaf(p, w, -0.00367342844f);
    p = fmaf(p, w, 0.00573950773f);
    p = fmaf(p, w, -0.0076224613f);
    p = fmaf(p, w, 0.00943887047f);
    p = fmaf(p, w, 1.00167406f);
    p = fmaf(p, w, 2.83297682f);
  }
  return p*x;
}

// 2-plane bf16 split (truncation): x ~= h+m with rel error <= 2^-16
__device__ __forceinline__ void split2(float x, unsigned short &h, unsigned short &m){
  uint32_t xb = __float_as_uint(x);
  h = (unsigned short)(xb >> 16);
  float r = x - __uint_as_float(xb & 0xFFFF0000u);
  m = (unsigned short)(__float_as_uint(r) >> 16);
}

#define MFMA(a,b,c) __builtin_amdgcn_mfma_f32_32x32x16_bf16((a),(b),(c),0,0,0)
// pack high-16s of two fp32: (x0>>16)|(x1&0xFFFF0000) in ONE v_perm_b32
#define PACKHI(x1,x0) __builtin_amdgcn_perm((x1),(x0),0x07060302u)

// DPP lane swaps (quad_perm): xor1 = 0xB1, xor2 = 0x4E. VALU-only (no DS pipe).
#define DPPPERM(v, CTRL) __int_as_float(__builtin_amdgcn_update_dpp( \
    0, __float_as_int(v), (CTRL), 0xF, 0xF, true))
#define DPPADD(v, CTRL) ((v) + DPPPERM((v), (CTRL)))

// LDS A-planes: 2 planes x 64 rows x 104 bf16 (208B rows). GEMM reads at the
// wave64 b128 minimum; strip-ownership writes keep sSW/sW13 reads broadcast
// (r14 proved coalesced writes destroy read broadcast at a net loss; r16 proved
// packed-fp32 rewrites add reg-pair moves at a net loss).
#define AROW 104
#define APLANE (64*AROW)

__global__ __launch_bounds__(256, 3) void cem_kernel(
    const float* __restrict__ states, const float* __restrict__ W1,
    const float* __restrict__ b1,     const float* __restrict__ W2,
    const float* __restrict__ b2,     const float* __restrict__ W3,
    const float* __restrict__ b3,     float* __restrict__ out)
{
  __shared__ __align__(16) unsigned short sApl[2*APLANE]; // 26624 B
  __shared__ float qbuf[2][64];
  __shared__ __align__(16) float sSW[HID];
  __shared__ __align__(16) float sW13[HID];
  __shared__ float sEps[64];
  __shared__ uint32_t sKeys[198];
  __shared__ float sB3;

  const int tid  = threadIdx.x;
  const int b    = blockIdx.x;
  const int wv   = tid >> 6;
  const int lane = tid & 63;
  const int half = lane >> 5;
  const int col  = lane & 31;
  // wave role: one M-tile (32 candidate rows), one N-pair (2 x 32 output cols)
  const int mt   = wv >> 1;            // 0,0,1,1
  const int np   = wv & 1;             // 0,1,0,1
  const int n0   = (2*np)*32 + col;
  const int n1   = (2*np+1)*32 + col;
  const int ewv  = (b + 1) & 3;        // eps wave (block-parity, overlapped)

  const float s0 = states[2*b], s1 = states[2*b+1];

  // zero-init A planes (pads must stay zero)
  for (int f = tid; f < APLANE; f += 256) ((unsigned int*)sApl)[f] = 0u;

  if (tid < HID){
    float w0 = W1[tid], w1 = W1[HID+tid];
    sSW[tid]  = fmaf(s0, w0, fmaf(s1, w1, b1[tid]));
    sW13[tid] = W1[2*HID+tid];
  }
  if (tid == 0) sB3 = b3[0];

  // per-lane epilogue constants (two N-tiles per wave)
  const float bn2_0 = (n0 < HID) ? b2[n0] : 0.0f;
  const float wn3_0 = (n0 < HID) ? W3[n0] : 0.0f;
  const float bn2_1 = (n1 < HID) ? b2[n1] : 0.0f;
  const float wn3_1 = (n1 < HID) ? W3[n1] : 0.0f;

  // one-time: static W2 B-fragments in registers (2-plane bf16 split), 2 N-tiles
  bf16x8 Bfh[2][7], Bfm[2][7];
#pragma unroll
  for (int j = 0; j < 2; ++j){
    const int n = j ? n1 : n0;
#pragma unroll
    for (int ks = 0; ks < 7; ++ks){
      FragU fh, fm;
#pragma unroll
      for (int i = 0; i < 8; ++i){
        int k = ks*16 + half*8 + i;
        float w = (k < HID && n < HID) ? W2[k*HID + n] : 0.0f;
        split2(w, fh.s[i], fm.s[i]);
      }
      Bfh[j][ks] = fh.v; Bfm[j][ks] = fm.v;
    }
  }

  // phase-1 fixed ownership: thread -> (candidate c_own, 20-wide k strip)
  const bool p1act = (tid < 250);
  const int  c_own = tid / 5;            // hoisted division (once)
  const int  k0own = (tid - c_own*5) * 20;
  const int  baseown = c_own*AROW + k0own;
  const int  rbase = (mt*32 + col)*AROW;

  // key schedule: key(42) = (0,42); split -> k0=(A0,B0), kloop=(A1,B1)
  if (tid < 99){
    uint32_t A0,A1,B0,B1;
    tf2x32(0u,42u,0u,2u,A0,A1);
    tf2x32(0u,42u,1u,3u,B0,B1);
    uint32_t o0,o1;
    tf2x32(A1,B1,(uint32_t)tid,(uint32_t)(99+tid),o0,o1);
    sKeys[tid]    = o0;
    sKeys[99+tid] = o1;
    if (tid < MCAND){
      // iteration-0 "eps" = uniform angles (mu=0, std=1 makes a_c = eps_c)
      uint32_t gidx = (uint32_t)b*MCAND + (uint32_t)tid;
      uint32_t r0,r1,bits;
      if (gidx < 102400u){ tf2x32(A0,B0,gidx,gidx+102400u,r0,r1); bits = r0; }
      else               { tf2x32(A0,B0,gidx-102400u,gidx,r0,r1); bits = r1; }
      sEps[tid] = __uint_as_float((bits>>9) | 0x3f800000u) - 1.0f;
    }
  }
  __syncthreads();

  const float MINV = -0x1.fffffep-1f;   // nextafter(-1,0)
  const float SQRT2 = 0x1.6a09e6p+0f;   // fp32 sqrt(2)

  float mu = 0.0f, stdv = 1.0f;         // per-wave redundant CEM state

#pragma unroll 1
  for (int t = 0; t < 99; ++t){
    // ---- phase 1: a_c = mu + std*eps_c; h1 = relu(sSW + a_c*sW13); split2 to LDS ----
    if (p1act){
      const float a = fmaf(stdv, sEps[c_own], mu);
#pragma unroll
      for (int i = 0; i < 5; ++i){
        const int k = k0own + 4*i;
        float4 sw  = *(const float4*)&sSW[k];
        float4 w13 = *(const float4*)&sW13[k];
        float v0 = fmaxf(fmaf(a, w13.x, sw.x), 0.0f);
        float v1 = fmaxf(fmaf(a, w13.y, sw.y), 0.0f);
        float v2 = fmaxf(fmaf(a, w13.z, sw.z), 0.0f);
        float v3 = fmaxf(fmaf(a, w13.w, sw.w), 0.0f);
        uint32_t x0 = __float_as_uint(v0), x1 = __float_as_uint(v1);
        uint32_t x2 = __float_as_uint(v2), x3 = __float_as_uint(v3);
        uint2 hq, mq;
        hq.x = PACKHI(x1, x0);
        hq.y = PACKHI(x3, x2);
        float r0 = v0 - __uint_as_float(x0 & 0xFFFF0000u);
        float r1 = v1 - __uint_as_float(x1 & 0xFFFF0000u);
        float r2 = v2 - __uint_as_float(x2 & 0xFFFF0000u);
        float r3 = v3 - __uint_as_float(x3 & 0xFFFF0000u);
        mq.x = PACKHI(__float_as_uint(r1), __float_as_uint(r0));
        mq.y = PACKHI(__float_as_uint(r3), __float_as_uint(r2));
        *(uint2*)&sApl[baseown + 4*i]          = hq;
        *(uint2*)&sApl[APLANE + baseown + 4*i] = mq;
      }
    }
    __syncthreads();   // B1

    // ---- phase 2: next-iter eps (block-parity wave, overlapped) + MFMA GEMM ----
    if (wv == ewv && t < 98 && lane < MCAND){
      uint32_t kk0 = sKeys[2*t], kk1 = sKeys[2*t+1];
      uint32_t gidx = (uint32_t)b*MCAND + (uint32_t)lane;
      uint32_t r0,r1,bits;
      if (gidx < 102400u){ tf2x32(kk0,kk1,gidx,gidx+102400u,r0,r1); bits = r0; }
      else               { tf2x32(kk0,kk1,gidx-102400u,gidx,r0,r1); bits = r1; }
      float fl = __uint_as_float((bits>>9) | 0x3f800000u) - 1.0f;
      float u  = fmaxf(MINV, fl*2.0f + MINV);
      sEps[lane] = SQRT2 * erfinv32(u);
    }

    {
      f32x16 acc0, acc1;   // two N-tiles, same M-tile
#pragma unroll
      for (int r = 0; r < 16; ++r){ acc0[r] = 0.0f; acc1[r] = 0.0f; }

#pragma unroll
      for (int ks = 0; ks < 7; ++ks){
        const int ra = rbase + ks*16 + half*8;
        bf16x8 ah = *(const bf16x8*)&sApl[ra];
        bf16x8 am = *(const bf16x8*)&sApl[APLANE + ra];
        // hh + hm + mh per N-tile (mm dropped: below 2-plane truncation noise)
        acc0 = MFMA(ah, Bfh[0][ks], acc0);
        acc1 = MFMA(ah, Bfh[1][ks], acc1);
        acc0 = MFMA(ah, Bfm[0][ks], acc0);
        acc1 = MFMA(ah, Bfm[1][ks], acc1);
        acc0 = MFMA(am, Bfh[0][ks], acc0);
        acc1 = MFMA(am, Bfh[1][ks], acc1);
      }

      // epilogue: per-N-tile relu+W3 scale, then SUM the two N-tiles
      // elementwise (same candidates!) -> single 32-col reduction
      float v[16];
#pragma unroll
      for (int r = 0; r < 16; ++r){
        v[r] = fmaxf(acc0[r] + bn2_0, 0.0f) * wn3_0
             + fmaxf(acc1[r] + bn2_1, 0.0f) * wn3_1;
      }
      // concentrated reduction: steps 0,1 on DPP (VALU), steps 2,3 on DS shuffle
      {
        const bool hi0 = (col & 1) != 0;
#pragma unroll
        for (int i = 0; i < 8; ++i){
          float a0 = DPPADD(v[2*i],   0xB1);
          float b0 = DPPADD(v[2*i+1], 0xB1);
          v[i] = hi0 ? b0 : a0;
        }
        const bool hi1 = (col & 2) != 0;
#pragma unroll
        for (int i = 0; i < 4; ++i){
          float a0 = DPPADD(v[2*i],   0x4E);
          float b0 = DPPADD(v[2*i+1], 0x4E);
          v[i] = hi1 ? b0 : a0;
        }
#pragma unroll
        for (int step = 2; step < 4; ++step){
          const int off = 1 << step;
          const bool hi = (col & off) != 0;
          const int nn = 16 >> step;
#pragma unroll
          for (int i = 0; i < nn/2; ++i){
            float a0 = v[2*i]   + __shfl_xor(v[2*i],   off, 64);
            float b0 = v[2*i+1] + __shfl_xor(v[2*i+1], off, 64);
            v[i] = hi ? b0 : a0;
          }
        }
      }
      float red = v[0] + __shfl_xor(v[0], 16, 64);
      const int c15 = col & 15;
      const int row = (c15 & 3) + 8*(c15 >> 2) + 4*half;
      if (col < 16) qbuf[np][mt*32 + row] = red;
    }
    __syncthreads();   // B2

    // ---- phase 3 (redundant on ALL 4 waves, DPP-cheap): top-32 stats in regs ----
    {
      float q = -INFINITY;
      if (lane < MCAND)
        q = qbuf[0][lane] + qbuf[1][lane] + sB3;
      // sort 32-halves in opposite directions, j=32 max-merge -> top-32 multiset
      float v = q;
#define BST(KK, JJ, PV) { float pv = (PV); bool lower = (lane & (JJ)) == 0; \
        bool asc = (lane & (KK)) != 0; float mn = fminf(v, pv), mx = fmaxf(v, pv); \
        v = (lower == asc) ? mn : mx; }
      BST(2, 1,  DPPPERM(v, 0xB1))
      BST(4, 2,  DPPPERM(v, 0x4E))
      BST(4, 1,  DPPPERM(v, 0xB1))
      BST(8, 4,  __shfl_xor(v, 4, 64))
      BST(8, 2,  DPPPERM(v, 0x4E))
      BST(8, 1,  DPPPERM(v, 0xB1))
      BST(16, 8, __shfl_xor(v, 8, 64))
      BST(16, 4, __shfl_xor(v, 4, 64))
      BST(16, 2, DPPPERM(v, 0x4E))
      BST(16, 1, DPPPERM(v, 0xB1))
      BST(32, 16, __shfl_xor(v, 16, 64))
      BST(32, 8,  __shfl_xor(v, 8, 64))
      BST(32, 4,  __shfl_xor(v, 4, 64))
      BST(32, 2,  DPPPERM(v, 0x4E))
      BST(32, 1,  DPPPERM(v, 0xB1))
#undef BST
      {
        float pv = __shfl_xor(v, 32, 64);
        v = ((lane & 32) == 0) ? fmaxf(v, pv) : fminf(v, pv);
      }
      // sum / sum-of-squares over lanes 0..31 (same add order as r13)
      float sv = (lane < NTOP) ? v : 0.0f;
      sv += __shfl_xor(sv, 32, 64);
      sv += __shfl_xor(sv, 16, 64);
      sv += __shfl_xor(sv,  8, 64);
      sv += __shfl_xor(sv,  4, 64);
      sv = DPPADD(sv, 0x4E);
      sv = DPPADD(sv, 0xB1);
      float mun = sv / 32.0f;
      float dv = (lane < NTOP) ? (v - mun) : 0.0f;
      float s2 = dv*dv;
      s2 += __shfl_xor(s2, 32, 64);
      s2 += __shfl_xor(s2, 16, 64);
      s2 += __shfl_xor(s2,  8, 64);
      s2 += __shfl_xor(s2,  4, 64);
      s2 = DPPADD(s2, 0x4E);
      s2 = DPPADD(s2, 0xB1);
      stdv = sqrtf(s2 / 31.0f);
      mu = mun;
      if (t == 98 && tid == 0) out[b] = mu * 6.2831854820251465f;  // fp32(2*pi)
    }
    // no B3: phase1(t+1) sApl writes race only vs phase2(t) reads (behind B2);
    // sEps(t+1) written before B2(t), read after B2(t); qbuf(t+1) written in
    // phase2(t+1) behind B1(t+1), after all phase3(t) reads. (r7-proven.)
  }
}

extern "C" void kernel_launch(void* const* d_in, const int* in_sizes, int n_in,
                              void* d_out, int out_size, void* d_ws, size_t ws_size,
                              hipStream_t stream) {
  const float* states = (const float*)d_in[0];
  const float* W1     = (const float*)d_in[1];
  const float* b1     = (const float*)d_in[2];
  const float* W2     = (const float*)d_in[3];
  const float* b2     = (const float*)d_in[4];
  const float* W3     = (const float*)d_in[5];
  const float* b3     = (const float*)d_in[6];
  float* out = (float*)d_out;
  hipLaunchKernelGGL(cem_kernel, dim3(BATCH), dim3(256), 0, stream,
                     states, W1, b1, W2, b2, W3, b3, out);
}